// Round 5
// baseline (125.774 us; speedup 1.0000x reference)
//
#include <hip/hip_runtime.h>
#include <hip/hip_cooperative_groups.h>
#include <math.h>

#define HW 16384  // 128*128

namespace cg = cooperative_groups;

// ---------------------------------------------------------------------------
// Single cooperative kernel. grid = B*64 = 512 blocks x 256 threads,
// 2 blocks/CU co-resident (VGPR capped by __launch_bounds__(256,2)).
//
// Phase A (per block, ~2-3us):
//   A1: modulation for channels j*8..j*8+7 of batch b  -> weff4 in ws
//   A2: attention energy for this block's 4x4-block columns -> energy, part
// grid.sync()
// Phase B: R2-exact 268MB streaming loop (proven best shape) + nt loads.
// ---------------------------------------------------------------------------
__global__ __launch_bounds__(256, 2) void fused_kernel(
    const float* __restrict__ input, const float* __restrict__ style,
    const float* __restrict__ skip, const float* __restrict__ a0in,
    const float* __restrict__ a1in, const float* __restrict__ conv_w,
    const float* __restrict__ mod_w, const float* __restrict__ mod_b,
    const float* __restrict__ bias, const float* __restrict__ q_w,
    const float* __restrict__ q_b, const float* __restrict__ upk,
    float4* __restrict__ weff4, float* __restrict__ energy,
    float* __restrict__ part, float* __restrict__ out) {
  __shared__ float4 lw[512];
  __shared__ float qw[27];
  __shared__ float qb;
  __shared__ float partl[4];
  __shared__ float ssq_sh;

  int t = threadIdx.x;
  int blk = blockIdx.x;
  int b = blk >> 6;
  int j = blk & 63;

  // ================= Phase A1: modulation slice =================
  // group g = t>>5 handles channel c = j*8+g; 32 lanes split the 512-dot.
  {
    int g = t >> 5, l = t & 31;
    int c = j * 8 + g;
    const float4* row = reinterpret_cast<const float4*>(mod_w + (size_t)c * 512);
    const float4* st = reinterpret_cast<const float4*>(style + (size_t)b * 512);
    float4 r0 = row[l], r1 = row[l + 32], r2 = row[l + 64], r3 = row[l + 96];
    float4 s0 = st[l], s1 = st[l + 32], s2 = st[l + 64], s3 = st[l + 96];
    float s = r0.x * s0.x + r0.y * s0.y + r0.z * s0.z + r0.w * s0.w +
              r1.x * s1.x + r1.y * s1.y + r1.z * s1.z + r1.w * s1.w +
              r2.x * s2.x + r2.y * s2.y + r2.z * s2.z + r2.w * s2.w +
              r3.x * s3.x + r3.y * s3.y + r3.z * s3.z + r3.w * s3.w;
#pragma unroll
    for (int m = 1; m < 32; m <<= 1) s += __shfl_xor(s, m);
    if (l == 0) {
      const float kInv = 0.04419417382415922f;  // 1/sqrt(512)
      s = s * kInv + mod_b[c];
      float4 o;
      o.x = conv_w[c] * kInv * s;
      o.y = conv_w[512 + c] * kInv * s;
      o.z = conv_w[1024 + c] * kInv * s;
      o.w = 0.f;
      weff4[(size_t)b * 512 + c] = o;
    }
  }

  // ================= Phase A2: attention energy (R2 mapping) =================
  {
    if (t < 27) qw[t] = q_w[t];
    if (t == 27) qb = q_b[0];
    __syncthreads();

    int colLocal = t >> 4;        // 0..15
    int pos = t & 15;             // 0..15
    int col = j * 16 + colLocal;  // 0..1023
    int by = col >> 5, bx = col & 31;
    int iy = pos >> 2, ix = pos & 3;
    int h = by * 4 + iy, w = bx * 4 + ix;

    float pq = qb, pk = qb;
#pragma unroll
    for (int ci = 0; ci < 3; ++ci) {
      const float* p0 = a0in + (size_t)(b * 3 + ci) * HW;
      const float* p1 = a1in + (size_t)(b * 3 + ci) * HW;
#pragma unroll
      for (int ky = 0; ky < 3; ++ky) {
        int hh = h + ky - 1;
        if ((unsigned)hh >= 128u) continue;
#pragma unroll
        for (int kx = 0; kx < 3; ++kx) {
          int ww = w + kx - 1;
          if ((unsigned)ww >= 128u) continue;
          float wq = qw[ci * 9 + ky * 3 + kx];
          pq = fmaf(wq, p0[hh * 128 + ww], pq);
          pk = fmaf(wq, p1[hh * 128 + ww], pk);
        }
      }
    }
    float sq = pq * pq, sk = pk * pk;
#pragma unroll
    for (int m = 1; m < 16; m <<= 1) {
      sq += __shfl_xor(sq, m);
      sk += __shfl_xor(sk, m);
    }
    float qn = 1.0f / fmaxf(sqrtf(sq), 1e-12f);
    float kn = 1.0f / fmaxf(sqrtf(sk), 1e-12f);
    float e = (pq * qn) * (pk * kn);
    energy[(size_t)b * HW + h * 128 + w] = e;

    float ss = e * e;
#pragma unroll
    for (int m = 1; m < 64; m <<= 1) ss += __shfl_xor(ss, m);
    int wid = t >> 6;
    if ((t & 63) == 0) partl[wid] = ss;
    __syncthreads();
    if (t == 0) part[blk] = partl[0] + partl[1] + partl[2] + partl[3];
  }

  __threadfence();
  cg::this_grid().sync();

  // ================= Phase B: R2-exact streaming =================
  int p = j * 256 + t;  // pixel 0..16383

  const float4* g4 = weff4 + (size_t)b * 512;
  float4 g0 = g4[t], g1 = g4[t + 256];
  if (t < 64) {
    float ps = part[b * 64 + t];
#pragma unroll
    for (int m = 1; m < 64; m <<= 1) ps += __shfl_xor(ps, m);
    if (t == 0) ssq_sh = ps;
  }
  lw[t] = g0;
  lw[t + 256] = g1;

  float e = energy[(size_t)b * HW + p];
  int y = p >> 7, x = p & 127;
  int syb = ((y + (y & 1)) >> 1) - 1;
  int sxb = ((x + (x & 1)) >> 1) - 1;
  int ky0 = y & 1, kx0 = x & 1;
  float s0 = 0.f, s1 = 0.f, s2 = 0.f;
#pragma unroll
  for (int a = 0; a < 2; ++a) {
    int sy = syb + a;
    if ((unsigned)sy >= 64u) continue;
#pragma unroll
    for (int c2 = 0; c2 < 2; ++c2) {
      int sx = sxb + c2;
      if ((unsigned)sx >= 64u) continue;
      float kv = upk[(ky0 + 2 * a) * 4 + (kx0 + 2 * c2)];
      size_t base = ((size_t)(b * 3) * 64 + sy) * 64 + sx;
      s0 = fmaf(kv, skip[base], s0);
      s1 = fmaf(kv, skip[base + 4096], s1);
      s2 = fmaf(kv, skip[base + 8192], s2);
    }
  }
  float bi0 = bias[0], bi1 = bias[1], bi2 = bias[2];

  __syncthreads();  // lw + ssq_sh ready

  const float* in = input + (size_t)b * 512 * HW + p;
  float a0 = 0.f, a1 = 0.f, a2 = 0.f;
  for (int c0 = 0; c0 < 512; c0 += 32) {
    float v[32];
#pragma unroll
    for (int u = 0; u < 32; ++u)
      v[u] = __builtin_nontemporal_load(in + (size_t)(c0 + u) * HW);
#pragma unroll
    for (int u = 0; u < 32; ++u) {
      float4 w = lw[c0 + u];
      a0 = fmaf(w.x, v[u], a0);
      a1 = fmaf(w.y, v[u], a1);
      a2 = fmaf(w.z, v[u], a2);
    }
  }

  float att = e * (4.0f / fmaxf(sqrtf(ssq_sh), 1e-12f));
  float om = 1.0f - att;
  size_t ob = (size_t)(b * 3) * HW + p;
  __builtin_nontemporal_store((a0 + bi0) * att + s0 * om, out + ob);
  __builtin_nontemporal_store((a1 + bi1) * att + s1 * om, out + ob + HW);
  __builtin_nontemporal_store((a2 + bi2) * att + s2 * om, out + ob + 2 * HW);
}

// ---------------------------------------------------------------------------
extern "C" void kernel_launch(void* const* d_in, const int* in_sizes, int n_in,
                              void* d_out, int out_size, void* d_ws,
                              size_t ws_size, hipStream_t stream) {
  const float* input  = (const float*)d_in[0];
  const float* style  = (const float*)d_in[1];
  const float* skip   = (const float*)d_in[2];
  const float* att0   = (const float*)d_in[3];
  const float* att1   = (const float*)d_in[4];
  const float* conv_w = (const float*)d_in[5];
  const float* mod_w  = (const float*)d_in[6];
  const float* mod_b  = (const float*)d_in[7];
  const float* bias   = (const float*)d_in[8];
  const float* q_w    = (const float*)d_in[9];
  const float* q_b    = (const float*)d_in[10];
  const float* upk    = (const float*)d_in[11];

  int B = in_sizes[1] / 512;  // 8

  float* ws = (float*)d_ws;
  float4* weff4 = (float4*)ws;          // B*512 float4
  float* energy = ws + 16384;           // B*HW
  float* part   = ws + 16384 + 131072;  // B*64
  float* outp   = (float*)d_out;

  void* args[] = {
      (void*)&input, (void*)&style, (void*)&skip,  (void*)&att0,
      (void*)&att1,  (void*)&conv_w, (void*)&mod_w, (void*)&mod_b,
      (void*)&bias,  (void*)&q_w,    (void*)&q_b,   (void*)&upk,
      (void*)&weff4, (void*)&energy, (void*)&part,  (void*)&outp};
  hipLaunchCooperativeKernel((void*)fused_kernel, dim3(B * 64), dim3(256),
                             args, 0, stream);
}

// Round 6
// 60.013 us; speedup vs baseline: 2.0958x; 2.0958x over previous
//
#include <hip/hip_runtime.h>
#include <math.h>

#define HW 16384       // 128*128
#define PX4 4096       // HW/4 float4 slots per channel plane
#define MOD_BLOCKS 1024

// ---------------------------------------------------------------------------
// Pre-kernel: R2-exact (proven 56.1us config).
//   blocks [0, MOD_BLOCKS):  modulation -> weff4[b][c] = {w0,w1,w2,0}
//   blocks [MOD_BLOCKS, ..): attention energy + per-block partial sumsq.
// ---------------------------------------------------------------------------
__global__ __launch_bounds__(256) void pre_kernel(
    const float* __restrict__ style, const float* __restrict__ mod_w,
    const float* __restrict__ mod_b, const float* __restrict__ conv_w,
    const float* __restrict__ a0in, const float* __restrict__ a1in,
    const float* __restrict__ q_w, const float* __restrict__ q_b,
    float4* __restrict__ weff4, float* __restrict__ energy,
    float* __restrict__ part) {
  int bid = blockIdx.x;
  int t = threadIdx.x;

  if (bid < MOD_BLOCKS) {
    int wg = bid * 4 + (t >> 6);  // 0..4095
    int b = wg >> 9;
    int i = wg & 511;
    int lane = t & 63;
    const float4* row = reinterpret_cast<const float4*>(mod_w + (size_t)i * 512);
    const float4* st = reinterpret_cast<const float4*>(style + (size_t)b * 512);
    float4 r0 = row[lane], r1 = row[lane + 64];
    float4 s0 = st[lane], s1 = st[lane + 64];
    float s = r0.x * s0.x + r0.y * s0.y + r0.z * s0.z + r0.w * s0.w +
              r1.x * s1.x + r1.y * s1.y + r1.z * s1.z + r1.w * s1.w;
#pragma unroll
    for (int m = 1; m < 64; m <<= 1) s += __shfl_xor(s, m);
    if (lane == 0) {
      const float kInv = 0.04419417382415922f;  // 1/sqrt(512)
      s = s * kInv + mod_b[i];
      float4 o;
      o.x = conv_w[i] * kInv * s;
      o.y = conv_w[512 + i] * kInv * s;
      o.z = conv_w[1024 + i] * kInv * s;
      o.w = 0.f;
      weff4[(size_t)b * 512 + i] = o;
    }
    return;
  }

  int blk = bid - MOD_BLOCKS;  // 0 .. B*64-1
  int b = blk >> 6;
  int j = blk & 63;
  int colLocal = t >> 4;        // 0..15
  int pos = t & 15;             // 0..15
  int col = j * 16 + colLocal;  // 0..1023
  int by = col >> 5, bx = col & 31;
  int iy = pos >> 2, ix = pos & 3;
  int h = by * 4 + iy, w = bx * 4 + ix;

  __shared__ float qw[27];
  __shared__ float qb;
  if (t < 27) qw[t] = q_w[t];
  if (t == 27) qb = q_b[0];
  __syncthreads();

  float pq = qb, pk = qb;
#pragma unroll
  for (int ci = 0; ci < 3; ++ci) {
    const float* p0 = a0in + (size_t)(b * 3 + ci) * HW;
    const float* p1 = a1in + (size_t)(b * 3 + ci) * HW;
#pragma unroll
    for (int ky = 0; ky < 3; ++ky) {
      int hh = h + ky - 1;
      if ((unsigned)hh >= 128u) continue;
#pragma unroll
      for (int kx = 0; kx < 3; ++kx) {
        int ww = w + kx - 1;
        if ((unsigned)ww >= 128u) continue;
        float wq = qw[ci * 9 + ky * 3 + kx];
        pq = fmaf(wq, p0[hh * 128 + ww], pq);
        pk = fmaf(wq, p1[hh * 128 + ww], pk);
      }
    }
  }
  float sq = pq * pq, sk = pk * pk;
#pragma unroll
  for (int m = 1; m < 16; m <<= 1) {
    sq += __shfl_xor(sq, m);
    sk += __shfl_xor(sk, m);
  }
  float qn = 1.0f / fmaxf(sqrtf(sq), 1e-12f);
  float kn = 1.0f / fmaxf(sqrtf(sk), 1e-12f);
  float e = (pq * qn) * (pk * kn);
  energy[(size_t)b * HW + h * 128 + w] = e;

  float ss = e * e;
#pragma unroll
  for (int m = 1; m < 64; m <<= 1) ss += __shfl_xor(ss, m);
  __shared__ float partl[4];
  int wid = t >> 6;
  if ((t & 63) == 0) partl[wid] = ss;
  __syncthreads();
  if (t == 0) part[blk] = partl[0] + partl[1] + partl[2] + partl[3];
}

// ---------------------------------------------------------------------------
// Main streaming kernel, R6: channel-split float4.
// 512 blocks x 256 threads (8 waves/CU, R2's occupancy). Block covers 256
// pixels (64 float4 slots). Wave w handles channels [128w,128w+128) over all
// 64 slots -> every wave-load is 1KB contiguous (4x R2's burst). Partial
// accumulators reduced across the 4 waves in LDS (stride-13 pad, <=2-way).
// ---------------------------------------------------------------------------
__global__ __launch_bounds__(256) void main_kernel(
    const float* __restrict__ input, const float4* __restrict__ weff4,
    const float* __restrict__ bias, const float* __restrict__ skip,
    const float* __restrict__ upk, const float* __restrict__ energy,
    const float* __restrict__ part, float* __restrict__ out) {
  __shared__ float4 lw[512];
  __shared__ float lds_part[4 * 64 * 13];  // [wave][slot][12 used of 13]
  __shared__ float ssq_sh;
  int t = threadIdx.x;
  int blk = blockIdx.x;
  int b = blk >> 6;
  int j = blk & 63;
  int s = t & 63;   // float4 slot within block
  int w = t >> 6;   // wave id -> channel band

  // ---- stage weff into LDS + reduce this batch's 64 sumsq partials ----
  const float4* g = weff4 + (size_t)b * 512;
  float4 g0 = g[t], g1 = g[t + 256];
  if (t < 64) {
    float ps = part[b * 64 + t];
#pragma unroll
    for (int m = 1; m < 64; m <<= 1) ps += __shfl_xor(ps, m);
    if (t == 0) ssq_sh = ps;
  }
  lw[t] = g0;
  lw[t + 256] = g1;

  // ---- epilogue inputs for pixel p = j*256 + t, loaded early ----
  int p = j * 256 + t;
  float e = energy[(size_t)b * HW + p];
  int y = p >> 7, x = p & 127;
  int syb = ((y + (y & 1)) >> 1) - 1;
  int sxb = ((x + (x & 1)) >> 1) - 1;
  int ky0 = y & 1, kx0 = x & 1;
  float sk0 = 0.f, sk1 = 0.f, sk2 = 0.f;
#pragma unroll
  for (int a = 0; a < 2; ++a) {
    int sy = syb + a;
    if ((unsigned)sy >= 64u) continue;
#pragma unroll
    for (int c2 = 0; c2 < 2; ++c2) {
      int sx = sxb + c2;
      if ((unsigned)sx >= 64u) continue;
      float kv = upk[(ky0 + 2 * a) * 4 + (kx0 + 2 * c2)];
      size_t base = ((size_t)(b * 3) * 64 + sy) * 64 + sx;
      sk0 = fmaf(kv, skip[base], sk0);
      sk1 = fmaf(kv, skip[base + 4096], sk1);
      sk2 = fmaf(kv, skip[base + 8192], sk2);
    }
  }
  float bi0 = bias[0], bi1 = bias[1], bi2 = bias[2];

  __syncthreads();  // lw + ssq_sh ready

  // ---- channel-band loop: 128 channels, chunks of 16 float4 ----
  const float4* in4 = reinterpret_cast<const float4*>(input) +
                      ((size_t)b * 512 + w * 128) * PX4 + (size_t)j * 64 + s;
  float A0[4] = {0.f, 0.f, 0.f, 0.f};
  float A1[4] = {0.f, 0.f, 0.f, 0.f};
  float A2[4] = {0.f, 0.f, 0.f, 0.f};
  int cbase = w * 128;
  for (int c0 = 0; c0 < 128; c0 += 16) {
    float4 v[16];
#pragma unroll
    for (int u = 0; u < 16; ++u) v[u] = in4[(size_t)(c0 + u) * PX4];
#pragma unroll
    for (int u = 0; u < 16; ++u) {
      float4 wv = lw[cbase + c0 + u];
      A0[0] = fmaf(wv.x, v[u].x, A0[0]);
      A0[1] = fmaf(wv.x, v[u].y, A0[1]);
      A0[2] = fmaf(wv.x, v[u].z, A0[2]);
      A0[3] = fmaf(wv.x, v[u].w, A0[3]);
      A1[0] = fmaf(wv.y, v[u].x, A1[0]);
      A1[1] = fmaf(wv.y, v[u].y, A1[1]);
      A1[2] = fmaf(wv.y, v[u].z, A1[2]);
      A1[3] = fmaf(wv.y, v[u].w, A1[3]);
      A2[0] = fmaf(wv.z, v[u].x, A2[0]);
      A2[1] = fmaf(wv.z, v[u].y, A2[1]);
      A2[2] = fmaf(wv.z, v[u].z, A2[2]);
      A2[3] = fmaf(wv.z, v[u].w, A2[3]);
    }
  }

  // ---- cross-wave reduction via LDS ----
  float* mp = &lds_part[(w * 64 + s) * 13];
#pragma unroll
  for (int i = 0; i < 4; ++i) {
    mp[i] = A0[i];
    mp[4 + i] = A1[i];
    mp[8 + i] = A2[i];
  }
  __syncthreads();

  // thread t finishes pixel p = j*256 + t: slot = t>>2, sub = t&3
  int slot = t >> 2, sub = t & 3;
  float a0 = 0.f, a1 = 0.f, a2 = 0.f;
#pragma unroll
  for (int ww = 0; ww < 4; ++ww) {
    const float* q = &lds_part[(ww * 64 + slot) * 13];
    a0 += q[sub];
    a1 += q[4 + sub];
    a2 += q[8 + sub];
  }

  float att = e * (4.0f / fmaxf(sqrtf(ssq_sh), 1e-12f));
  float om = 1.0f - att;
  size_t ob = (size_t)(b * 3) * HW + p;
  out[ob] = (a0 + bi0) * att + sk0 * om;
  out[ob + HW] = (a1 + bi1) * att + sk1 * om;
  out[ob + 2 * HW] = (a2 + bi2) * att + sk2 * om;
}

// ---------------------------------------------------------------------------
extern "C" void kernel_launch(void* const* d_in, const int* in_sizes, int n_in,
                              void* d_out, int out_size, void* d_ws,
                              size_t ws_size, hipStream_t stream) {
  const float* input  = (const float*)d_in[0];
  const float* style  = (const float*)d_in[1];
  const float* skip   = (const float*)d_in[2];
  const float* att0   = (const float*)d_in[3];
  const float* att1   = (const float*)d_in[4];
  const float* conv_w = (const float*)d_in[5];
  const float* mod_w  = (const float*)d_in[6];
  const float* mod_b  = (const float*)d_in[7];
  const float* bias   = (const float*)d_in[8];
  const float* q_w    = (const float*)d_in[9];
  const float* q_b    = (const float*)d_in[10];
  const float* upk    = (const float*)d_in[11];

  int B = in_sizes[1] / 512;  // 8

  float* ws = (float*)d_ws;
  float4* weff4 = (float4*)ws;          // B*512 float4
  float* energy = ws + 16384;           // B*HW
  float* part   = ws + 16384 + 131072;  // B*64

  pre_kernel<<<MOD_BLOCKS + B * 64, 256, 0, stream>>>(
      style, mod_w, mod_b, conv_w, att0, att1, q_w, q_b, weff4, energy, part);
  main_kernel<<<B * 64, 256, 0, stream>>>(input, weff4, bias, skip, upk,
                                          energy, part, (float*)d_out);
}